// Round 15
// baseline (464.686 us; speedup 1.0000x reference)
//
#include <hip/hip_runtime.h>
#include <hip/hip_cooperative_groups.h>

namespace cg = cooperative_groups;

#define ROWS 16384                      /* points per side */
#define PTS_TOTAL 32768

#define LOG2E 1.4426950408889634f
#define LN2   0.6931471805599453f
#define NEG_LOG2M (-12.0f)              /* -log2(4096) */
#define EPS1LNM 8.317766166719343e-4f   /* eps1 * ln(4096) */
#define ENC_STRIDE 32

typedef _Float16 h2 __attribute__((ext_vector_type(2)));
typedef _Float16 v8h __attribute__((ext_vector_type(8)));
typedef float f32x4 __attribute__((ext_vector_type(4)));

__device__ inline float fexp2(float x) { return __builtin_amdgcn_exp2f(x); }
__device__ inline float flog2(float x) { return __builtin_amdgcn_logf(x); }

__device__ inline unsigned fenc(float f) {
  unsigned u = __float_as_uint(f);
  return (u & 0x80000000u) ? ~u : (u | 0x80000000u);
}
__device__ inline float fdec(unsigned u) {
  return (u & 0x80000000u) ? __uint_as_float(u & 0x7fffffffu)
                           : __uint_as_float(~u);
}
__device__ inline unsigned pkh2(float a, float b) {
  h2 hv; hv.x = (_Float16)a; hv.y = (_Float16)b;
  return __builtin_bit_cast(unsigned, hv);
}
__device__ inline v8h bcv8(uint4 u) { return __builtin_bit_cast(v8h, u); }

__device__ inline float taylor_f(const float* __restrict__ M, const float* v,
                                 float q, float eps0) {
  float sc2 = 2.0f * LOG2E / eps0;
  float p[6];
#pragma unroll
  for (int d = 0; d < 6; ++d) p[d] = v[d] * sc2;
  float t1 = 0.0f;
#pragma unroll
  for (int d = 0; d < 6; ++d) t1 += p[d] * M[1 + d];
  float t2 = 0.0f;
  int kk = 7;
#pragma unroll
  for (int d = 0; d < 6; ++d) {
#pragma unroll
    for (int e = d; e < 6; ++e) {
      float coef = (d == e) ? 1.0f : 2.0f;
      t2 += coef * p[d] * p[e] * M[kk];
      kk++;
    }
  }
  float S = M[0] + LN2 * t1 + (0.5f * LN2 * LN2) * t2;
  return q - eps0 * LN2 * flog2(S);
}

// 28-entry weighted-moment accumulate
__device__ inline void mom_acc(float w, const float* v, float* acc) {
  acc[0] = w;
  int kk = 1;
#pragma unroll
  for (int d = 0; d < 6; ++d) acc[kk++] = w * v[d];
#pragma unroll
  for (int d = 0; d < 6; ++d) {
    float wv = w * v[d];
#pragma unroll
    for (int e = d; e < 6; ++e) acc[kk++] = wv * v[e];
  }
}

// ======================= cooperative mega-kernel ===========================
__global__ __launch_bounds__(256, 2) void mega_kernel(
    const float* __restrict__ x, const float* __restrict__ y,
    float* __restrict__ out, unsigned* __restrict__ enc,
    float* __restrict__ MOM, uint4* __restrict__ AREC,
    uint4* __restrict__ BRECA, uint4* __restrict__ BRECB,
    float* __restrict__ Q, float* __restrict__ FG2,
    float* __restrict__ PART) {
  cg::grid_group grid = cg::this_grid();
  const int t = threadIdx.x;
  const int blk = blockIdx.x;
  const int gtid = blk * 256 + t;         // 0..131071
  const int wave = t >> 6, lane = t & 63;
  float* MOM1 = MOM;
  float* MOM2 = MOM + 256;

  __shared__ unsigned shu[4][13];
  __shared__ float shm[4][28];
  __shared__ float lm[4][64];
  __shared__ float fsh[64];
  __shared__ float red[256];

  // ---- P0: init enc + moments ----
  if (gtid < 13) enc[gtid * ENC_STRIDE] = 0u;
  if (gtid < 512) MOM[gtid] = 0.0f;
  grid.sync();

  // ---- P1: 13 flip-encoded global maxes (blocks 0..127) ----
  if (blk < 128) {
    bool isx = gtid < ROWS;
    const float* p = (isx ? x : y) + (size_t)(isx ? gtid : gtid - ROWS) * 6;
    float d[6];
#pragma unroll
    for (int k = 0; k < 6; ++k) d[k] = p[k];
    unsigned e[13];
    e[0] = fenc(d[0] * d[0] + d[1] * d[1] + d[2] * d[2]);
#pragma unroll
    for (int k = 0; k < 6; ++k) {
      e[1 + k] = fenc(d[k]);
      e[7 + k] = fenc(-d[k]);
    }
#pragma unroll
    for (int off = 32; off > 0; off >>= 1) {
#pragma unroll
      for (int k = 0; k < 13; ++k) {
        unsigned o = (unsigned)__shfl_xor((int)e[k], off);
        e[k] = e[k] > o ? e[k] : o;
      }
    }
    if (lane == 0) {
#pragma unroll
      for (int k = 0; k < 13; ++k) shu[wave][k] = e[k];
    }
    __syncthreads();
    if (t < 13) {
      unsigned v2 = shu[0][t];
#pragma unroll
      for (int w = 1; w < 4; ++w) v2 = v2 > shu[w][t] ? v2 : shu[w][t];
      atomicMax(&enc[t * ENC_STRIDE], v2);
    }
  }
  grid.sync();

  float v[6] = {0, 0, 0, 0, 0, 0};
  float q = 0.0f, eps0 = 1.0f, f1 = 0.0f;
  int side = gtid >> 14, batch = (gtid & (ROWS - 1)) >> 12;

  // ---- P2: pack + mom1 partials ----
  if (blk < 128) {
    float s = 1.0f / (sqrtf(fdec(enc[0])) + 1e-6f);
    eps0 = 0.0f;
#pragma unroll
    for (int k = 0; k < 6; ++k) {
      float dd = fdec(enc[(1 + k) * ENC_STRIDE]) +
                 fdec(enc[(7 + k) * ENC_STRIDE]);
      eps0 += dd * dd;
    }
    int local = gtid & (ROWS - 1);
    const float* p = (side ? y : x) + (size_t)local * 6;
    v[0] = p[0] * s; v[1] = p[1] * s; v[2] = p[2] * s;
    v[3] = 0.1f * fminf(fmaxf(p[3], 0.0f), 1.0f);
    v[4] = 0.1f * fminf(fmaxf(p[4], 0.0f), 1.0f);
    v[5] = 0.1f * fminf(fmaxf(p[5], 0.0f), 1.0f);
    q = v[0]*v[0] + v[1]*v[1] + v[2]*v[2] + v[3]*v[3] + v[4]*v[4] + v[5]*v[5];
    Q[gtid] = q;
    unsigned w01 = pkh2(v[0], v[1]), w23 = pkh2(v[2], v[3]),
             w45 = pkh2(v[4], v[5]);
    AREC[gtid]  = (uint4){w01, w23, w45, pkh2(1.0f, 0.0f)};
    BRECA[gtid] = (uint4){w01, w23, w45, 0u};

    float acc[28];
    mom_acc(fexp2(NEG_LOG2M - q * (LOG2E / eps0)), v, acc);
#pragma unroll
    for (int off = 32; off > 0; off >>= 1) {
#pragma unroll
      for (int k = 0; k < 28; ++k) acc[k] += __shfl_xor(acc[k], off);
    }
    if (lane == 0) {
#pragma unroll
      for (int k = 0; k < 28; ++k) shm[wave][k] = acc[k];
    }
    __syncthreads();
    if (t < 28) {
      float vv = (shm[0][t] + shm[1][t]) + (shm[2][t] + shm[3][t]);
      atomicAdd(&MOM1[(side * 4 + batch) * 32 + t], vv);
    }
  }
  grid.sync();

  // ---- P3: rows pair-1 + mom2 partials ----
  if (blk < 128) {
    const float* M = MOM1 + (((side ^ 1) * 4 + batch) * 32);
    f1 = taylor_f(M, v, q, eps0);
    float acc[28];
    mom_acc(fexp2(NEG_LOG2M + (f1 - q) * (LOG2E / eps0)), v, acc);
#pragma unroll
    for (int off = 32; off > 0; off >>= 1) {
#pragma unroll
      for (int k = 0; k < 28; ++k) acc[k] += __shfl_xor(acc[k], off);
    }
    if (lane == 0) {
#pragma unroll
      for (int k = 0; k < 28; ++k) shm[wave][k] = acc[k];
    }
    __syncthreads();
    if (t < 28) {
      float vv = (shm[0][t] + shm[1][t]) + (shm[2][t] + shm[3][t]);
      atomicAdd(&MOM2[(side * 4 + batch) * 32 + t], vv);
    }
  }
  grid.sync();

  // ---- P4: rows pair-2 -> FG2, hs2 into BRECA.w ----
  if (blk < 128) {
    const float* M = MOM2 + (((side ^ 1) * 4 + batch) * 32);
    float f_t = taylor_f(M, v, q, eps0);
    float f2v = 0.5f * (f1 + f_t);
    FG2[gtid] = f2v;
    ((unsigned*)BRECA)[4 * gtid + 3] = pkh2(0.5f * (f2v - q - EPS1LNM), 0.0f);
  }
  grid.sync();

  // ---- MFMA phases: block = 64 rows (4 A-tiles), wave = 1024-col quarter --
  const int grow0 = blk * 64;
  const int mside = grow0 >> 14;
  const int mbatch = (grow0 & (ROWS - 1)) >> 12;
  const int colrec0 = (mside ^ 1) * ROWS + mbatch * 4096 + wave * 1024;
  const int l16 = lane & 15;
  const bool ld = lane < 16;
  const uint4 z4 = (uint4){0u, 0u, 0u, 0u};
  v8h a[4];
#pragma unroll
  for (int i = 0; i < 4; ++i) {
    uint4 au = z4;
    if (ld) au = AREC[grow0 + i * 16 + l16];
    a[i] = bcv8(au);
  }
  const f32x4 cz = {0.0f, 0.0f, 0.0f, 0.0f};

#pragma unroll
  for (int phase = 0; phase < 2; ++phase) {
    const uint4* __restrict__ BIN = (phase == 0) ? BRECA : BRECB;
    f32x4 m2[4];
#pragma unroll
    for (int i = 0; i < 4; ++i)
      m2[i] = (f32x4){-3.0e38f, -3.0e38f, -3.0e38f, -3.0e38f};
#pragma unroll 4
    for (int tt = 0; tt < 64; ++tt) {
      uint4 bu = z4;
      if (ld) bu = BIN[colrec0 + tt * 16 + l16];
      v8h b = bcv8(bu);
#pragma unroll
      for (int i = 0; i < 4; ++i) {
        f32x4 d = __builtin_amdgcn_mfma_f32_16x16x32_f16(a[i], b, cz, 0, 0, 0);
        m2[i] = __builtin_elementwise_max(m2[i], d);
      }
    }
#pragma unroll
    for (int off = 1; off <= 8; off <<= 1) {
#pragma unroll
      for (int i = 0; i < 4; ++i) {
#pragma unroll
        for (int r = 0; r < 4; ++r)
          m2[i][r] = fmaxf(m2[i][r], __shfl_xor(m2[i][r], off));
      }
    }
    if (l16 == 0) {
      int qd = lane >> 4;
#pragma unroll
      for (int i = 0; i < 4; ++i) {
#pragma unroll
        for (int r = 0; r < 4; ++r) lm[wave][i * 16 + qd * 4 + r] = m2[i][r];
      }
    }
    __syncthreads();
    if (phase == 0) {
      if (t < 64) {
        int g = grow0 + t;
        float m = fmaxf(fmaxf(lm[0][t], lm[1][t]), fmaxf(lm[2][t], lm[3][t]));
        float qq = Q[g];
        float fo = 0.5f * (FG2[g] + (qq - 2.0f * m));
        uint4 ar = AREC[g];
        BRECB[g] = (uint4){ar.x, ar.y, ar.z,
                           pkh2(0.5f * (fo - qq - EPS1LNM), 0.0f)};
      }
      grid.sync();
    } else {
      if (t < 64) {
        int g = grow0 + t;
        float m = fmaxf(fmaxf(lm[0][t], lm[1][t]), fmaxf(lm[2][t], lm[3][t]));
        fsh[t] = Q[g] - 2.0f * m;
      }
      __syncthreads();
      if (t == 0) {
        float ssum = 0.0f;
#pragma unroll
        for (int k = 0; k < 64; ++k) ssum += fsh[k];
        PART[blk] = ssum;
      }
      grid.sync();
    }
  }

  // ---- P7: final mean (block 0 over 512 partials) ----
  if (blk == 0) {
    float acc = (t < 512 - 256) ? PART[256 + t] : 0.0f;
    acc += PART[t];
    red[t] = acc;
    __syncthreads();
    for (int st = 128; st > 0; st >>= 1) {
      if (t < st) red[t] += red[t + st];
      __syncthreads();
    }
    if (t == 0) out[0] = red[0] * (10.0f / (float)ROWS);
  }
}

// ======================= fallback pipeline (R13) ===========================
__global__ void init_kernel(unsigned* enc, float* MOM) {
  int t = threadIdx.x;
  if (t < 13) enc[t * ENC_STRIDE] = 0u;
  if (t < 512) MOM[t] = 0.0f;
}

__global__ __launch_bounds__(256) void reduce_kernel(
    const float* __restrict__ x, const float* __restrict__ y,
    unsigned* __restrict__ enc) {
  int idx = blockIdx.x * 256 + threadIdx.x;
  bool isx = idx < ROWS;
  const float* p = (isx ? x : y) + (size_t)(isx ? idx : idx - ROWS) * 6;
  float d[6];
#pragma unroll
  for (int k = 0; k < 6; ++k) d[k] = p[k];
  unsigned e[13];
  e[0] = fenc(d[0] * d[0] + d[1] * d[1] + d[2] * d[2]);
#pragma unroll
  for (int k = 0; k < 6; ++k) {
    e[1 + k] = fenc(d[k]);
    e[7 + k] = fenc(-d[k]);
  }
#pragma unroll
  for (int off = 32; off > 0; off >>= 1) {
#pragma unroll
    for (int k = 0; k < 13; ++k) {
      unsigned o = (unsigned)__shfl_xor((int)e[k], off);
      e[k] = e[k] > o ? e[k] : o;
    }
  }
  __shared__ unsigned sh[4][13];
  int wave = threadIdx.x >> 6, lane = threadIdx.x & 63;
  if (lane == 0) {
#pragma unroll
    for (int k = 0; k < 13; ++k) sh[wave][k] = e[k];
  }
  __syncthreads();
  if (threadIdx.x < 13) {
    unsigned v = sh[0][threadIdx.x];
#pragma unroll
    for (int w = 1; w < 4; ++w)
      v = v > sh[w][threadIdx.x] ? v : sh[w][threadIdx.x];
    atomicMax(&enc[threadIdx.x * ENC_STRIDE], v);
  }
}

__global__ __launch_bounds__(256) void pack_kernel(
    const float* __restrict__ x, const float* __restrict__ y,
    float* __restrict__ Q, float* __restrict__ V6, uint4* __restrict__ AREC,
    uint4* __restrict__ BREC, const unsigned* __restrict__ enc,
    float* __restrict__ sc, float* __restrict__ MOM1) {
  int g = blockIdx.x * 256 + threadIdx.x;
  int side = g >> 14, local = g & (ROWS - 1), batch = local >> 12;
  float s = 1.0f / (sqrtf(fdec(enc[0])) + 1e-6f);
  float eps0 = 0.0f;
#pragma unroll
  for (int k = 0; k < 6; ++k) {
    float dd = fdec(enc[(1 + k) * ENC_STRIDE]) + fdec(enc[(7 + k) * ENC_STRIDE]);
    eps0 += dd * dd;
  }
  if (g == 0) sc[0] = eps0;
  const float* p = (side ? y : x) + (size_t)local * 6;
  float v[6];
  v[0] = p[0] * s; v[1] = p[1] * s; v[2] = p[2] * s;
  v[3] = 0.1f * fminf(fmaxf(p[3], 0.0f), 1.0f);
  v[4] = 0.1f * fminf(fmaxf(p[4], 0.0f), 1.0f);
  v[5] = 0.1f * fminf(fmaxf(p[5], 0.0f), 1.0f);
  float q = v[0]*v[0] + v[1]*v[1] + v[2]*v[2] + v[3]*v[3] + v[4]*v[4] + v[5]*v[5];
  Q[g] = q;
#pragma unroll
  for (int d = 0; d < 6; ++d) V6[(size_t)g * 6 + d] = v[d];
  unsigned w01 = pkh2(v[0], v[1]), w23 = pkh2(v[2], v[3]),
           w45 = pkh2(v[4], v[5]);
  AREC[g] = (uint4){w01, w23, w45, pkh2(1.0f, 0.0f)};
  BREC[g] = (uint4){w01, w23, w45, 0u};

  float acc[28];
  mom_acc(fexp2(NEG_LOG2M - q * (LOG2E / eps0)), v, acc);
#pragma unroll
  for (int off = 32; off > 0; off >>= 1) {
#pragma unroll
    for (int k = 0; k < 28; ++k) acc[k] += __shfl_xor(acc[k], off);
  }
  __shared__ float sh[4][28];
  int wave = threadIdx.x >> 6, lane = threadIdx.x & 63;
  if (lane == 0) {
#pragma unroll
    for (int k = 0; k < 28; ++k) sh[wave][k] = acc[k];
  }
  __syncthreads();
  if (threadIdx.x < 28) {
    float vv = (sh[0][threadIdx.x] + sh[1][threadIdx.x]) +
               (sh[2][threadIdx.x] + sh[3][threadIdx.x]);
    atomicAdd(&MOM1[(side * 4 + batch) * 32 + threadIdx.x], vv);
  }
}

__global__ __launch_bounds__(256) void rows1_kernel(
    const float* __restrict__ Q, const float* __restrict__ V6,
    const float* __restrict__ MOM1, float* __restrict__ MOM2,
    float* __restrict__ FG1, const float* __restrict__ sc) {
  int g = blockIdx.x * 256 + threadIdx.x;
  int side = g >> 14, local = g & (ROWS - 1), batch = local >> 12;
  float eps0 = sc[0];
  float v[6];
#pragma unroll
  for (int d = 0; d < 6; ++d) v[d] = V6[(size_t)g * 6 + d];
  float q = Q[g];
  const float* M = MOM1 + (((side ^ 1) * 4 + batch) * 32);
  float f1 = taylor_f(M, v, q, eps0);
  FG1[g] = f1;
  float acc[28];
  mom_acc(fexp2(NEG_LOG2M + (f1 - q) * (LOG2E / eps0)), v, acc);
#pragma unroll
  for (int off = 32; off > 0; off >>= 1) {
#pragma unroll
    for (int k = 0; k < 28; ++k) acc[k] += __shfl_xor(acc[k], off);
  }
  __shared__ float sh[4][28];
  int wave = threadIdx.x >> 6, lane = threadIdx.x & 63;
  if (lane == 0) {
#pragma unroll
    for (int k = 0; k < 28; ++k) sh[wave][k] = acc[k];
  }
  __syncthreads();
  if (threadIdx.x < 28) {
    float vv = (sh[0][threadIdx.x] + sh[1][threadIdx.x]) +
               (sh[2][threadIdx.x] + sh[3][threadIdx.x]);
    atomicAdd(&MOM2[(side * 4 + batch) * 32 + threadIdx.x], vv);
  }
}

__global__ __launch_bounds__(256) void rows2_kernel(
    const float* __restrict__ Q, const float* __restrict__ V6,
    const float* __restrict__ MOM2, const float* __restrict__ FG1,
    float* __restrict__ FG2, unsigned* __restrict__ BRECu,
    const float* __restrict__ sc) {
  int g = blockIdx.x * 256 + threadIdx.x;
  int side = g >> 14, local = g & (ROWS - 1), batch = local >> 12;
  float eps0 = sc[0];
  float v[6];
#pragma unroll
  for (int d = 0; d < 6; ++d) v[d] = V6[(size_t)g * 6 + d];
  float q = Q[g];
  const float* M = MOM2 + (((side ^ 1) * 4 + batch) * 32);
  float f_t = taylor_f(M, v, q, eps0);
  float f2v = 0.5f * (FG1[g] + f_t);
  FG2[g] = f2v;
  BRECu[4 * g + 3] = pkh2(0.5f * (f2v - q - EPS1LNM), 0.0f);
}

__global__ __launch_bounds__(256) void softmax_pair_kernel(
    const uint4* __restrict__ AREC, const uint4* __restrict__ BIN,
    uint4* __restrict__ BOUT, const float* __restrict__ Q,
    const float* __restrict__ prev, float* __restrict__ part) {
  int t = threadIdx.x;
  int wave = t >> 6, lane = t & 63;
  int l16 = lane & 15;
  bool ld = lane < 16;
  int grow0 = blockIdx.x * 32;
  int side = grow0 >> 14;
  int batch = (grow0 & (ROWS - 1)) >> 12;
  int colrec0 = (side ^ 1) * ROWS + batch * 4096 + wave * 1024;
  uint4 z4 = (uint4){0u, 0u, 0u, 0u};
  uint4 a1u = z4, a2u = z4;
  if (ld) {
    a1u = AREC[grow0 + l16];
    a2u = AREC[grow0 + 16 + l16];
  }
  v8h a1 = bcv8(a1u), a2 = bcv8(a2u);
  f32x4 m2a = {-3.0e38f, -3.0e38f, -3.0e38f, -3.0e38f};
  f32x4 m2b = m2a;
  const f32x4 cz = {0.0f, 0.0f, 0.0f, 0.0f};
#pragma unroll 4
  for (int tt = 0; tt < 64; ++tt) {
    uint4 bu = z4;
    if (ld) bu = BIN[colrec0 + tt * 16 + l16];
    v8h b = bcv8(bu);
    f32x4 d1 = __builtin_amdgcn_mfma_f32_16x16x32_f16(a1, b, cz, 0, 0, 0);
    f32x4 d2 = __builtin_amdgcn_mfma_f32_16x16x32_f16(a2, b, cz, 0, 0, 0);
    m2a = __builtin_elementwise_max(m2a, d1);
    m2b = __builtin_elementwise_max(m2b, d2);
  }
#pragma unroll
  for (int off = 1; off <= 8; off <<= 1) {
#pragma unroll
    for (int r = 0; r < 4; ++r) {
      m2a[r] = fmaxf(m2a[r], __shfl_xor(m2a[r], off));
      m2b[r] = fmaxf(m2b[r], __shfl_xor(m2b[r], off));
    }
  }
  __shared__ float lm[4][32];
  __shared__ float fsh[32];
  if (l16 == 0) {
    int qd = lane >> 4;
#pragma unroll
    for (int r = 0; r < 4; ++r) {
      lm[wave][qd * 4 + r] = m2a[r];
      lm[wave][16 + qd * 4 + r] = m2b[r];
    }
  }
  __syncthreads();
  if (t < 32) {
    int g = grow0 + t;
    float m = fmaxf(fmaxf(lm[0][t], lm[1][t]), fmaxf(lm[2][t], lm[3][t]));
    float q = Q[g];
    float f_t = q - 2.0f * m;
    float fo = prev ? 0.5f * (prev[g] + f_t) : f_t;
    if (BOUT) {
      uint4 ar = AREC[g];
      BOUT[g] = (uint4){ar.x, ar.y, ar.z,
                        pkh2(0.5f * (fo - q - EPS1LNM), 0.0f)};
    }
    if (part) fsh[t] = fo;
  }
  __syncthreads();
  if (part && t == 0) {
    float ssum = 0.0f;
#pragma unroll
    for (int k = 0; k < 32; ++k) ssum += fsh[k];
    part[blockIdx.x] = ssum;
  }
}

__global__ __launch_bounds__(256) void final_kernel(
    const float* __restrict__ part, int n, float* __restrict__ out) {
  float acc = 0.0f;
  for (int i = threadIdx.x; i < n; i += 256) acc += part[i];
  __shared__ float sh[256];
  sh[threadIdx.x] = acc;
  __syncthreads();
  for (int st = 128; st > 0; st >>= 1) {
    if (threadIdx.x < st) sh[threadIdx.x] += sh[threadIdx.x + st];
    __syncthreads();
  }
  if (threadIdx.x == 0) out[0] = sh[0] * (10.0f / (float)ROWS);
}

extern "C" void kernel_launch(void* const* d_in, const int* in_sizes, int n_in,
                              void* d_out, int out_size, void* d_ws,
                              size_t ws_size, hipStream_t stream) {
  const float* x = (const float*)d_in[0];
  const float* y = (const float*)d_in[1];
  float* out = (float*)d_out;
  float* w = (float*)d_ws;
  unsigned* enc = (unsigned*)d_ws;            // 13 slots at stride 32
  float* sc  = w + 448;
  float* MOM = w + 512;                       // 512 floats
  float* MOM1 = MOM;
  float* MOM2 = MOM + 256;
  float* base = w + 1024;
  uint4* AREC  = (uint4*)base;                // 131072 words
  uint4* BRECA = (uint4*)(base + 131072);
  uint4* BRECB = (uint4*)(base + 262144);
  float* Q    = base + 393216;                // 32768
  float* V6   = Q + PTS_TOTAL;                // 196608
  float* FG1  = V6 + 6 * PTS_TOTAL;           // 32768
  float* FG2  = FG1 + PTS_TOTAL;              // 32768
  float* PART = FG2 + PTS_TOTAL;              // 1024

  // capacity check for the cooperative path (queries only; capture-safe)
  int capacity = 0;
  {
    int nb = 0;
    if (hipOccupancyMaxActiveBlocksPerMultiprocessor(
            &nb, (const void*)mega_kernel, 256, 0) == hipSuccess) {
      hipDeviceProp_t prop;
      int dev = 0;
      hipGetDevice(&dev);
      if (hipGetDeviceProperties(&prop, dev) == hipSuccess)
        capacity = nb * prop.multiProcessorCount;
    }
  }

  if (capacity >= 512) {
    void* args[] = {(void*)&x,    (void*)&y,     (void*)&out,   (void*)&enc,
                    (void*)&MOM,  (void*)&AREC,  (void*)&BRECA, (void*)&BRECB,
                    (void*)&Q,    (void*)&FG2,   (void*)&PART};
    hipLaunchCooperativeKernel((const void*)mega_kernel, dim3(512), dim3(256),
                               args, 0, stream);
  } else {
    init_kernel<<<1, 512, 0, stream>>>(enc, MOM);
    reduce_kernel<<<PTS_TOTAL / 256, 256, 0, stream>>>(x, y, enc);
    pack_kernel<<<PTS_TOTAL / 256, 256, 0, stream>>>(x, y, Q, V6, AREC, BRECA,
                                                     enc, sc, MOM1);
    rows1_kernel<<<PTS_TOTAL / 256, 256, 0, stream>>>(Q, V6, MOM1, MOM2, FG1,
                                                      sc);
    rows2_kernel<<<PTS_TOTAL / 256, 256, 0, stream>>>(Q, V6, MOM2, FG1, FG2,
                                                      (unsigned*)BRECA, sc);
    softmax_pair_kernel<<<1024, 256, 0, stream>>>(AREC, BRECA, BRECB, Q, FG2,
                                                  nullptr);
    softmax_pair_kernel<<<1024, 256, 0, stream>>>(AREC, BRECB, nullptr, Q,
                                                  nullptr, PART);
    final_kernel<<<1, 256, 0, stream>>>(PART, 1024, out);
  }
}

// Round 16
// 246.376 us; speedup vs baseline: 1.8861x; 1.8861x over previous
//
#include <hip/hip_runtime.h>

#define ROWS 16384
#define PTS_TOTAL 32768
#define NBLK 256

#define LOG2E 1.4426950408889634f
#define LN2   0.6931471805599453f
#define NEG_LOG2M (-12.0f)              /* -log2(4096) */
#define EPS1LNM 8.317766166719343e-4f   /* eps1 * ln(4096) */

typedef _Float16 h2 __attribute__((ext_vector_type(2)));
typedef _Float16 v8h __attribute__((ext_vector_type(8)));
typedef float f32x4 __attribute__((ext_vector_type(4)));

__device__ inline float fexp2(float x) { return __builtin_amdgcn_exp2f(x); }
__device__ inline float flog2(float x) { return __builtin_amdgcn_logf(x); }
__device__ inline unsigned pkh2(float a, float b) {
  h2 hv; hv.x = (_Float16)a; hv.y = (_Float16)b;
  return __builtin_bit_cast(unsigned, hv);
}
__device__ inline v8h bcv8(uint4 u) { return __builtin_bit_cast(v8h, u); }

__device__ inline float taylor_f(const float* M, const float* v, float q,
                                 float eps0) {
  float sc2 = 2.0f * LOG2E / eps0;
  float p[6];
#pragma unroll
  for (int d = 0; d < 6; ++d) p[d] = v[d] * sc2;
  float t1 = 0.0f;
#pragma unroll
  for (int d = 0; d < 6; ++d) t1 += p[d] * M[1 + d];
  float t2 = 0.0f;
  int kk = 7;
#pragma unroll
  for (int d = 0; d < 6; ++d) {
#pragma unroll
    for (int e = d; e < 6; ++e) {
      float coef = (d == e) ? 1.0f : 2.0f;
      t2 += coef * p[d] * p[e] * M[kk];
      kk++;
    }
  }
  float S = M[0] + LN2 * t1 + (0.5f * LN2 * LN2) * t2;
  return q - eps0 * LN2 * flog2(S);
}

__device__ inline void mom_acc(float w, const float* v, float* acc) {
  acc[0] = w;
  int kk = 1;
#pragma unroll
  for (int d = 0; d < 6; ++d) acc[kk++] = w * v[d];
#pragma unroll
  for (int d = 0; d < 6; ++d) {
    float wv = w * v[d];
#pragma unroll
    for (int e = d; e < 6; ++e) acc[kk++] = wv * v[e];
  }
}

// hand-rolled device-wide sense barrier: 1 atomic/block + relaxed spin.
// co-residency guaranteed: NBLK=256 blocks on 256 CUs, VGPR<=256 via bounds.
__device__ inline void gbar(unsigned* cnt, unsigned* gen) {
  __syncthreads();
  if (threadIdx.x == 0) {
    __threadfence();
    unsigned g = __hip_atomic_load(gen, __ATOMIC_RELAXED,
                                   __HIP_MEMORY_SCOPE_AGENT);
    unsigned a = __hip_atomic_fetch_add(cnt, 1u, __ATOMIC_ACQ_REL,
                                        __HIP_MEMORY_SCOPE_AGENT);
    if (a == NBLK - 1) {
      __hip_atomic_store(cnt, 0u, __ATOMIC_RELAXED, __HIP_MEMORY_SCOPE_AGENT);
      __hip_atomic_fetch_add(gen, 1u, __ATOMIC_ACQ_REL,
                             __HIP_MEMORY_SCOPE_AGENT);
    } else {
      while (__hip_atomic_load(gen, __ATOMIC_RELAXED,
                               __HIP_MEMORY_SCOPE_AGENT) == g)
        __builtin_amdgcn_s_sleep(1);
    }
    __threadfence();
  }
  __syncthreads();
}

// init: zero barrier state + out (ws/out are re-poisoned before every call)
__global__ void init_kernel(unsigned* bar, float* out) {
  if (threadIdx.x == 0) { bar[0] = 0u; bar[1] = 0u; out[0] = 0.0f; }
}

// ============ single fused Sinkhorn kernel, 5 internal barriers ============
__global__ __launch_bounds__(256, 2) void mega_kernel(
    const float* __restrict__ x, const float* __restrict__ y,
    float* __restrict__ out, unsigned* __restrict__ bar,
    float* __restrict__ MAXP,                  // [13][256]
    float* __restrict__ MOMP1,                 // [256][32]
    float* __restrict__ MOMP2,                 // [256][32]
    uint4* __restrict__ AREC, uint4* __restrict__ BRECA,
    uint4* __restrict__ BRECB) {
  const int t = threadIdx.x;
  const int blk = blockIdx.x;
  const int wave = t >> 6, lane = t & 63;
  unsigned* cnt = bar;
  unsigned* gen = bar + 1;

  __shared__ float shred[2][28];
  __shared__ float shfin[28];
  __shared__ float lm[4][128];
  __shared__ float ssum2[2];

  // ---- P1: per-block 13-max partials (t<128: one point each) ----
  const int idx = blk * 128 + t;               // 0..32767 for t<128
  if (t < 128) {
    bool isx = idx < ROWS;
    const float* p = (isx ? x : y) + (size_t)(isx ? idx : idx - ROWS) * 6;
    float d[6];
#pragma unroll
    for (int k = 0; k < 6; ++k) d[k] = p[k];
    float e[13];
    e[0] = d[0] * d[0] + d[1] * d[1] + d[2] * d[2];
#pragma unroll
    for (int k = 0; k < 6; ++k) {
      e[1 + k] = d[k];
      e[7 + k] = -d[k];
    }
#pragma unroll
    for (int off = 32; off > 0; off >>= 1) {
#pragma unroll
      for (int k = 0; k < 13; ++k) e[k] = fmaxf(e[k], __shfl_xor(e[k], off));
    }
    if (lane == 0) {
#pragma unroll
      for (int k = 0; k < 13; ++k) shred[wave][k] = e[k];
    }
  }
  __syncthreads();
  if (t < 13) MAXP[t * NBLK + blk] = fmaxf(shred[0][t], shred[1][t]);
  gbar(cnt, gen);                                            // B1

  // ---- P2: finalize maxes (wave0), pack, mom1 partials ----
  if (wave == 0) {
    for (int k = 0; k < 13; ++k) {
      float m = -3.0e38f;
      for (int j = lane; j < NBLK; j += 64) m = fmaxf(m, MAXP[k * NBLK + j]);
#pragma unroll
      for (int off = 32; off > 0; off >>= 1) m = fmaxf(m, __shfl_xor(m, off));
      if (lane == 0) shfin[k] = m;
    }
  }
  __syncthreads();
  float eps0 = 0.0f;
  {
    float acc = 0.0f;
#pragma unroll
    for (int k = 0; k < 6; ++k) {
      float dd = shfin[1 + k] + shfin[7 + k];
      acc += dd * dd;
    }
    eps0 = acc;
  }
  const float s = 1.0f / (sqrtf(shfin[0]) + 1e-6f);
  __syncthreads();

  float v[6] = {0, 0, 0, 0, 0, 0};
  float q = 0.0f, f1 = 0.0f, f2v = 0.0f;
  unsigned w01 = 0, w23 = 0, w45 = 0;
  if (t < 128) {
    bool isx = idx < ROWS;
    int local = isx ? idx : idx - ROWS;
    const float* p = (isx ? x : y) + (size_t)local * 6;
    v[0] = p[0] * s; v[1] = p[1] * s; v[2] = p[2] * s;
    v[3] = 0.1f * fminf(fmaxf(p[3], 0.0f), 1.0f);
    v[4] = 0.1f * fminf(fmaxf(p[4], 0.0f), 1.0f);
    v[5] = 0.1f * fminf(fmaxf(p[5], 0.0f), 1.0f);
    q = v[0]*v[0] + v[1]*v[1] + v[2]*v[2] + v[3]*v[3] + v[4]*v[4] + v[5]*v[5];
    w01 = pkh2(v[0], v[1]); w23 = pkh2(v[2], v[3]); w45 = pkh2(v[4], v[5]);
    AREC[idx]  = (uint4){w01, w23, w45, pkh2(1.0f, 0.0f)};
    BRECA[idx] = (uint4){w01, w23, w45, 0u};
    float acc[28];
    mom_acc(fexp2(NEG_LOG2M - q * (LOG2E / eps0)), v, acc);
#pragma unroll
    for (int off = 32; off > 0; off >>= 1) {
#pragma unroll
      for (int k = 0; k < 28; ++k) acc[k] += __shfl_xor(acc[k], off);
    }
    if (lane == 0) {
#pragma unroll
      for (int k = 0; k < 28; ++k) shred[wave][k] = acc[k];
    }
  }
  __syncthreads();
  if (t < 28) MOMP1[blk * 32 + t] = shred[0][t] + shred[1][t];
  gbar(cnt, gen);                                            // B2

  // ---- P3: rows pair-1 + mom2 partials ----
  const int g0 = (blk >> 5) << 5;              // first block of my group
  if (t < 28) {
    float ssum = 0.0f;
    for (int b = g0; b < g0 + 32; ++b) ssum += MOMP1[b * 32 + t];
    shfin[t] = ssum;
  }
  __syncthreads();
  if (t < 128) {
    f1 = taylor_f(shfin, v, q, eps0);
    float acc[28];
    mom_acc(fexp2(NEG_LOG2M + (f1 - q) * (LOG2E / eps0)), v, acc);
#pragma unroll
    for (int off = 32; off > 0; off >>= 1) {
#pragma unroll
      for (int k = 0; k < 28; ++k) acc[k] += __shfl_xor(acc[k], off);
    }
    if (lane == 0) {
#pragma unroll
      for (int k = 0; k < 28; ++k) shred[wave][k] = acc[k];
    }
  }
  __syncthreads();
  if (t < 28) MOMP2[blk * 32 + t] = shred[0][t] + shred[1][t];
  gbar(cnt, gen);                                            // B3

  // ---- P4: rows pair-2 -> f2v (register) + hs2 into BRECA.w ----
  if (t < 28) {
    float ssum = 0.0f;
    for (int b = g0; b < g0 + 32; ++b) ssum += MOMP2[b * 32 + t];
    shfin[t] = ssum;
  }
  __syncthreads();
  if (t < 128) {
    float f_t = taylor_f(shfin, v, q, eps0);
    f2v = 0.5f * (f1 + f_t);
    ((unsigned*)BRECA)[4 * idx + 3] = pkh2(0.5f * (f2v - q - EPS1LNM), 0.0f);
  }
  gbar(cnt, gen);                                            // B4

  // ---- MFMA phases: block = 128 rows (8 A-tiles), wave = 1024-col quarter
  const int grow0 = blk * 128;
  const int mside = grow0 >> 14;
  const int mbatch = (grow0 & (ROWS - 1)) >> 12;
  const int colrec0 = (mside ^ 1) * ROWS + mbatch * 4096 + wave * 1024;
  const int l16 = lane & 15;
  const bool ld = lane < 16;
  const uint4 z4 = (uint4){0u, 0u, 0u, 0u};
  v8h a[8];
#pragma unroll
  for (int i = 0; i < 8; ++i) {
    uint4 au = z4;
    if (ld) au = AREC[grow0 + i * 16 + l16];
    a[i] = bcv8(au);
  }
  const f32x4 cz = {0.0f, 0.0f, 0.0f, 0.0f};

#pragma unroll
  for (int phase = 0; phase < 2; ++phase) {
    const uint4* __restrict__ BIN = (phase == 0) ? BRECA : BRECB;
    f32x4 m2[8];
#pragma unroll
    for (int i = 0; i < 8; ++i)
      m2[i] = (f32x4){-3.0e38f, -3.0e38f, -3.0e38f, -3.0e38f};
#pragma unroll 4
    for (int tt = 0; tt < 64; ++tt) {
      uint4 bu = z4;
      if (ld) bu = BIN[colrec0 + tt * 16 + l16];
      v8h b = bcv8(bu);
#pragma unroll
      for (int i = 0; i < 8; ++i) {
        f32x4 d = __builtin_amdgcn_mfma_f32_16x16x32_f16(a[i], b, cz, 0, 0, 0);
        m2[i] = __builtin_elementwise_max(m2[i], d);
      }
    }
#pragma unroll
    for (int off = 1; off <= 8; off <<= 1) {
#pragma unroll
      for (int i = 0; i < 8; ++i) {
#pragma unroll
        for (int r = 0; r < 4; ++r)
          m2[i][r] = fmaxf(m2[i][r], __shfl_xor(m2[i][r], off));
      }
    }
    __syncthreads();                 // protect lm reuse across phases
    if (l16 == 0) {
      int qd = lane >> 4;
#pragma unroll
      for (int i = 0; i < 8; ++i) {
#pragma unroll
        for (int r = 0; r < 4; ++r) lm[wave][i * 16 + qd * 4 + r] = m2[i][r];
      }
    }
    __syncthreads();
    if (phase == 0) {
      if (t < 128) {
        float m = fmaxf(fmaxf(lm[0][t], lm[1][t]), fmaxf(lm[2][t], lm[3][t]));
        float fo = 0.5f * (f2v + (q - 2.0f * m));
        BRECB[idx] = (uint4){w01, w23, w45,
                             pkh2(0.5f * (fo - q - EPS1LNM), 0.0f)};
      }
      gbar(cnt, gen);                                        // B5
    } else {
      float fo = 0.0f;
      if (t < 128) {
        float m = fmaxf(fmaxf(lm[0][t], lm[1][t]), fmaxf(lm[2][t], lm[3][t]));
        fo = q - 2.0f * m;
#pragma unroll
        for (int off = 32; off > 0; off >>= 1) fo += __shfl_xor(fo, off);
        if (lane == 0) ssum2[wave] = fo;
      }
      __syncthreads();
      if (t == 0)
        atomicAdd(out, (ssum2[0] + ssum2[1]) * (10.0f / (float)ROWS));
    }
  }
}

extern "C" void kernel_launch(void* const* d_in, const int* in_sizes, int n_in,
                              void* d_out, int out_size, void* d_ws,
                              size_t ws_size, hipStream_t stream) {
  const float* x = (const float*)d_in[0];
  const float* y = (const float*)d_in[1];
  float* out = (float*)d_out;
  float* w = (float*)d_ws;
  unsigned* bar = (unsigned*)d_ws;            // [0]=cnt, [1]=gen
  float* MAXP  = w + 64;                      // 13*256 = 3328
  float* MOMP1 = w + 4096;                    // 256*32 = 8192
  float* MOMP2 = w + 12288;                   // 8192
  float* base  = w + 32768;
  uint4* AREC  = (uint4*)base;                // 32768 * 16 B
  uint4* BRECA = (uint4*)(base + 131072);
  uint4* BRECB = (uint4*)(base + 262144);

  init_kernel<<<1, 64, 0, stream>>>(bar, out);
  mega_kernel<<<NBLK, 256, 0, stream>>>(x, y, out, bar, MAXP, MOMP1, MOMP2,
                                        AREC, BRECA, BRECB);
}

// Round 17
// 228.583 us; speedup vs baseline: 2.0329x; 1.0778x over previous
//
#include <hip/hip_runtime.h>

#define ROWS 16384
#define PTS_TOTAL 32768
#define NBLK 256

#define LOG2E 1.4426950408889634f
#define LN2   0.6931471805599453f
#define NEG_LOG2M (-12.0f)              /* -log2(4096) */
#define EPS1LNM 8.317766166719343e-4f   /* eps1 * ln(4096) */

typedef _Float16 h2 __attribute__((ext_vector_type(2)));
typedef _Float16 v8h __attribute__((ext_vector_type(8)));
typedef float f32x4 __attribute__((ext_vector_type(4)));

__device__ inline float fexp2(float x) { return __builtin_amdgcn_exp2f(x); }
__device__ inline float flog2(float x) { return __builtin_amdgcn_logf(x); }
__device__ inline unsigned pkh2(float a, float b) {
  h2 hv; hv.x = (_Float16)a; hv.y = (_Float16)b;
  return __builtin_bit_cast(unsigned, hv);
}
__device__ inline v8h bcv8(uint4 u) { return __builtin_bit_cast(v8h, u); }

__device__ inline float taylor_f(const float* M, const float* v, float q,
                                 float eps0) {
  float sc2 = 2.0f * LOG2E / eps0;
  float p[6];
#pragma unroll
  for (int d = 0; d < 6; ++d) p[d] = v[d] * sc2;
  float t1 = 0.0f;
#pragma unroll
  for (int d = 0; d < 6; ++d) t1 += p[d] * M[1 + d];
  float t2 = 0.0f;
  int kk = 7;
#pragma unroll
  for (int d = 0; d < 6; ++d) {
#pragma unroll
    for (int e = d; e < 6; ++e) {
      float coef = (d == e) ? 1.0f : 2.0f;
      t2 += coef * p[d] * p[e] * M[kk];
      kk++;
    }
  }
  float S = M[0] + LN2 * t1 + (0.5f * LN2 * LN2) * t2;
  return q - eps0 * LN2 * flog2(S);
}

__device__ inline void mom_acc(float w, const float* v, float* acc) {
  acc[0] = w;
  int kk = 1;
#pragma unroll
  for (int d = 0; d < 6; ++d) acc[kk++] = w * v[d];
#pragma unroll
  for (int d = 0; d < 6; ++d) {
    float wv = w * v[d];
#pragma unroll
    for (int e = d; e < 6; ++e) acc[kk++] = wv * v[e];
  }
}

// device-wide sense barrier. cnt and gen on SEPARATE 128B lines so spin
// traffic (gen) never contends with arrival RMWs (cnt). Scoped atomics
// carry the release/acquire cache ops (no explicit threadfence).
__device__ inline void gbar(unsigned* cnt, unsigned* gen) {
  __syncthreads();
  if (threadIdx.x == 0) {
    unsigned g = __hip_atomic_load(gen, __ATOMIC_RELAXED,
                                   __HIP_MEMORY_SCOPE_AGENT);
    unsigned a = __hip_atomic_fetch_add(cnt, 1u, __ATOMIC_ACQ_REL,
                                        __HIP_MEMORY_SCOPE_AGENT);
    if (a == NBLK - 1) {
      __hip_atomic_store(cnt, 0u, __ATOMIC_RELAXED, __HIP_MEMORY_SCOPE_AGENT);
      __hip_atomic_fetch_add(gen, 1u, __ATOMIC_ACQ_REL,
                             __HIP_MEMORY_SCOPE_AGENT);
    } else if (__hip_atomic_load(gen, __ATOMIC_ACQUIRE,
                                 __HIP_MEMORY_SCOPE_AGENT) == g) {
      do {
        __builtin_amdgcn_s_sleep(8);
      } while (__hip_atomic_load(gen, __ATOMIC_ACQUIRE,
                                 __HIP_MEMORY_SCOPE_AGENT) == g);
    }
  }
  __syncthreads();
}

// init: zero barrier state + out
__global__ void init_kernel(unsigned* bar, float* out) {
  if (threadIdx.x < 64) bar[threadIdx.x] = 0u;
  if (threadIdx.x == 0) out[0] = 0.0f;
}

// ============ single fused Sinkhorn kernel, 5 internal barriers ============
__global__ __launch_bounds__(256, 2) void mega_kernel(
    const float* __restrict__ x, const float* __restrict__ y,
    float* __restrict__ out, unsigned* __restrict__ bar,
    float* __restrict__ MAXP,                  // [13][256]
    float* __restrict__ MOMP1,                 // [256][32]
    float* __restrict__ MOMP2,                 // [256][32]
    uint4* __restrict__ AREC, uint4* __restrict__ BRECA,
    uint4* __restrict__ BRECB) {
  const int t = threadIdx.x;
  const int blk = blockIdx.x;
  const int wave = t >> 6, lane = t & 63;
  unsigned* cnt = bar;            // line 0
  unsigned* gen = bar + 32;       // line 1 (128 B apart)

  __shared__ float shred[2][28];
  __shared__ float shfin[28];
  __shared__ float lm[4][128];
  __shared__ float ssum2[2];

  // ---- P1: per-block 13-max partials (t<128: one point each) ----
  const int idx = blk * 128 + t;               // 0..32767 for t<128
  if (t < 128) {
    bool isx = idx < ROWS;
    const float* p = (isx ? x : y) + (size_t)(isx ? idx : idx - ROWS) * 6;
    float d[6];
#pragma unroll
    for (int k = 0; k < 6; ++k) d[k] = p[k];
    float e[13];
    e[0] = d[0] * d[0] + d[1] * d[1] + d[2] * d[2];
#pragma unroll
    for (int k = 0; k < 6; ++k) {
      e[1 + k] = d[k];
      e[7 + k] = -d[k];
    }
#pragma unroll
    for (int off = 32; off > 0; off >>= 1) {
#pragma unroll
      for (int k = 0; k < 13; ++k) e[k] = fmaxf(e[k], __shfl_xor(e[k], off));
    }
    if (lane == 0) {
#pragma unroll
      for (int k = 0; k < 13; ++k) shred[wave][k] = e[k];
    }
  }
  __syncthreads();
  if (t < 13) MAXP[t * NBLK + blk] = fmaxf(shred[0][t], shred[1][t]);
  gbar(cnt, gen);                                            // B1

  // ---- P2: finalize maxes (wave0), pack, mom1 partials ----
  if (wave == 0) {
    for (int k = 0; k < 13; ++k) {
      float m = -3.0e38f;
      for (int j = lane; j < NBLK; j += 64) m = fmaxf(m, MAXP[k * NBLK + j]);
#pragma unroll
      for (int off = 32; off > 0; off >>= 1) m = fmaxf(m, __shfl_xor(m, off));
      if (lane == 0) shfin[k] = m;
    }
  }
  __syncthreads();
  float eps0 = 0.0f;
  {
    float acc = 0.0f;
#pragma unroll
    for (int k = 0; k < 6; ++k) {
      float dd = shfin[1 + k] + shfin[7 + k];
      acc += dd * dd;
    }
    eps0 = acc;
  }
  const float s = 1.0f / (sqrtf(shfin[0]) + 1e-6f);
  __syncthreads();

  float v[6] = {0, 0, 0, 0, 0, 0};
  float q = 0.0f, f1 = 0.0f, f2v = 0.0f;
  unsigned w01 = 0, w23 = 0, w45 = 0;
  if (t < 128) {
    bool isx = idx < ROWS;
    int local = isx ? idx : idx - ROWS;
    const float* p = (isx ? x : y) + (size_t)local * 6;
    v[0] = p[0] * s; v[1] = p[1] * s; v[2] = p[2] * s;
    v[3] = 0.1f * fminf(fmaxf(p[3], 0.0f), 1.0f);
    v[4] = 0.1f * fminf(fmaxf(p[4], 0.0f), 1.0f);
    v[5] = 0.1f * fminf(fmaxf(p[5], 0.0f), 1.0f);
    q = v[0]*v[0] + v[1]*v[1] + v[2]*v[2] + v[3]*v[3] + v[4]*v[4] + v[5]*v[5];
    w01 = pkh2(v[0], v[1]); w23 = pkh2(v[2], v[3]); w45 = pkh2(v[4], v[5]);
    AREC[idx]  = (uint4){w01, w23, w45, pkh2(1.0f, 0.0f)};
    BRECA[idx] = (uint4){w01, w23, w45, 0u};
    float acc[28];
    mom_acc(fexp2(NEG_LOG2M - q * (LOG2E / eps0)), v, acc);
#pragma unroll
    for (int off = 32; off > 0; off >>= 1) {
#pragma unroll
      for (int k = 0; k < 28; ++k) acc[k] += __shfl_xor(acc[k], off);
    }
    if (lane == 0) {
#pragma unroll
      for (int k = 0; k < 28; ++k) shred[wave][k] = acc[k];
    }
  }
  __syncthreads();
  if (t < 28) MOMP1[blk * 32 + t] = shred[0][t] + shred[1][t];
  gbar(cnt, gen);                                            // B2

  // ---- P3: rows pair-1 + mom2 partials ----
  const int g0 = (blk >> 5) << 5;              // first block of my batch group
  if (t < 28) {
    float ssum = 0.0f;
    for (int b = g0; b < g0 + 32; ++b) ssum += MOMP1[b * 32 + t];
    shfin[t] = ssum;
  }
  __syncthreads();
  if (t < 128) {
    f1 = taylor_f(shfin, v, q, eps0);
    float acc[28];
    mom_acc(fexp2(NEG_LOG2M + (f1 - q) * (LOG2E / eps0)), v, acc);
#pragma unroll
    for (int off = 32; off > 0; off >>= 1) {
#pragma unroll
      for (int k = 0; k < 28; ++k) acc[k] += __shfl_xor(acc[k], off);
    }
    if (lane == 0) {
#pragma unroll
      for (int k = 0; k < 28; ++k) shred[wave][k] = acc[k];
    }
  }
  __syncthreads();
  if (t < 28) MOMP2[blk * 32 + t] = shred[0][t] + shred[1][t];
  gbar(cnt, gen);                                            // B3

  // ---- P4: rows pair-2 -> f2v (register) + hs2 into BRECA.w ----
  if (t < 28) {
    float ssum = 0.0f;
    for (int b = g0; b < g0 + 32; ++b) ssum += MOMP2[b * 32 + t];
    shfin[t] = ssum;
  }
  __syncthreads();
  if (t < 128) {
    float f_t = taylor_f(shfin, v, q, eps0);
    f2v = 0.5f * (f1 + f_t);
    ((unsigned*)BRECA)[4 * idx + 3] = pkh2(0.5f * (f2v - q - EPS1LNM), 0.0f);
  }
  gbar(cnt, gen);                                            // B4

  // ---- MFMA phases: block = 128 rows (8 A-tiles), wave = 1024-col quarter
  const int grow0 = blk * 128;
  const int mside = grow0 >> 14;
  const int mbatch = (grow0 & (ROWS - 1)) >> 12;
  const int colrec0 = (mside ^ 1) * ROWS + mbatch * 4096 + wave * 1024;
  const int l16 = lane & 15;
  const bool ld = lane < 16;
  const uint4 z4 = (uint4){0u, 0u, 0u, 0u};
  v8h a[8];
#pragma unroll
  for (int i = 0; i < 8; ++i) {
    uint4 au = z4;
    if (ld) au = AREC[grow0 + i * 16 + l16];
    a[i] = bcv8(au);
  }
  const f32x4 cz = {0.0f, 0.0f, 0.0f, 0.0f};

#pragma unroll
  for (int phase = 0; phase < 2; ++phase) {
    const uint4* __restrict__ BIN = (phase == 0) ? BRECA : BRECB;
    f32x4 m2[8];
#pragma unroll
    for (int i = 0; i < 8; ++i)
      m2[i] = (f32x4){-3.0e38f, -3.0e38f, -3.0e38f, -3.0e38f};
#pragma unroll 4
    for (int tt = 0; tt < 64; ++tt) {
      uint4 bu = z4;
      if (ld) bu = BIN[colrec0 + tt * 16 + l16];
      v8h b = bcv8(bu);
#pragma unroll
      for (int i = 0; i < 8; ++i) {
        f32x4 d = __builtin_amdgcn_mfma_f32_16x16x32_f16(a[i], b, cz, 0, 0, 0);
        m2[i] = __builtin_elementwise_max(m2[i], d);
      }
    }
#pragma unroll
    for (int off = 1; off <= 8; off <<= 1) {
#pragma unroll
      for (int i = 0; i < 8; ++i) {
#pragma unroll
        for (int r = 0; r < 4; ++r)
          m2[i][r] = fmaxf(m2[i][r], __shfl_xor(m2[i][r], off));
      }
    }
    __syncthreads();                 // protect lm reuse across phases
    if (l16 == 0) {
      int qd = lane >> 4;
#pragma unroll
      for (int i = 0; i < 8; ++i) {
#pragma unroll
        for (int r = 0; r < 4; ++r) lm[wave][i * 16 + qd * 4 + r] = m2[i][r];
      }
    }
    __syncthreads();
    if (phase == 0) {
      if (t < 128) {
        float m = fmaxf(fmaxf(lm[0][t], lm[1][t]), fmaxf(lm[2][t], lm[3][t]));
        float fo = 0.5f * (f2v + (q - 2.0f * m));
        BRECB[idx] = (uint4){w01, w23, w45,
                             pkh2(0.5f * (fo - q - EPS1LNM), 0.0f)};
      }
      gbar(cnt, gen);                                        // B5
    } else {
      float fo = 0.0f;
      if (t < 128) {
        float m = fmaxf(fmaxf(lm[0][t], lm[1][t]), fmaxf(lm[2][t], lm[3][t]));
        fo = q - 2.0f * m;
#pragma unroll
        for (int off = 32; off > 0; off >>= 1) fo += __shfl_xor(fo, off);
        if (lane == 0) ssum2[wave] = fo;
      }
      __syncthreads();
      if (t == 0)
        atomicAdd(out, (ssum2[0] + ssum2[1]) * (10.0f / (float)ROWS));
    }
  }
}

extern "C" void kernel_launch(void* const* d_in, const int* in_sizes, int n_in,
                              void* d_out, int out_size, void* d_ws,
                              size_t ws_size, hipStream_t stream) {
  const float* x = (const float*)d_in[0];
  const float* y = (const float*)d_in[1];
  float* out = (float*)d_out;
  float* w = (float*)d_ws;
  unsigned* bar = (unsigned*)d_ws;            // [0]=cnt, [32]=gen
  float* MAXP  = w + 64;                      // 13*256 = 3328
  float* MOMP1 = w + 4096;                    // 256*32 = 8192
  float* MOMP2 = w + 12288;                   // 8192
  float* base  = w + 32768;
  uint4* AREC  = (uint4*)base;                // 32768 * 16 B
  uint4* BRECA = (uint4*)(base + 131072);
  uint4* BRECB = (uint4*)(base + 262144);

  init_kernel<<<1, 64, 0, stream>>>(bar, out);
  mega_kernel<<<NBLK, 256, 0, stream>>>(x, y, out, bar, MAXP, MOMP1, MOMP2,
                                        AREC, BRECA, BRECB);
}

// Round 18
// 163.521 us; speedup vs baseline: 2.8417x; 1.3979x over previous
//
#include <hip/hip_runtime.h>

#define ROWS 16384
#define PTS 32768

#define LOG2E 1.4426950408889634f
#define LN2   0.6931471805599453f
#define NEG_LOG2M (-12.0f)              /* -log2(4096) */
#define EPS1LNM 8.317766166719343e-4f   /* eps1 * ln(4096) */

typedef _Float16 h2 __attribute__((ext_vector_type(2)));
typedef _Float16 v8h __attribute__((ext_vector_type(8)));
typedef float f32x4 __attribute__((ext_vector_type(4)));

__device__ inline float fexp2(float x) { return __builtin_amdgcn_exp2f(x); }
__device__ inline float flog2(float x) { return __builtin_amdgcn_logf(x); }
__device__ inline unsigned pkh2(float a, float b) {
  h2 hv; hv.x = (_Float16)a; hv.y = (_Float16)b;
  return __builtin_bit_cast(unsigned, hv);
}
__device__ inline v8h bcv8(uint4 u) { return __builtin_bit_cast(v8h, u); }

// Taylor quadratic S = W + ln2*(p.M1) + ln2^2/2 * p^T M2 p
__device__ inline float taylor_S(const float* M, const float* v, float eps0) {
  float sc2 = 2.0f * LOG2E / eps0;
  float p[6];
#pragma unroll
  for (int d = 0; d < 6; ++d) p[d] = v[d] * sc2;
  float t1 = 0.0f;
#pragma unroll
  for (int d = 0; d < 6; ++d) t1 += p[d] * M[1 + d];
  float t2 = 0.0f;
  int kk = 7;
#pragma unroll
  for (int d = 0; d < 6; ++d) {
#pragma unroll
    for (int e = d; e < 6; ++e) {
      float coef = (d == e) ? 1.0f : 2.0f;
      t2 += coef * p[d] * p[e] * M[kk];
      ++kk;
    }
  }
  return M[0] + LN2 * t1 + (0.5f * LN2 * LN2) * t2;
}

__device__ inline void mom_acc(float w, const float* v, float* acc) {
  acc[0] = w;
  int kk = 1;
#pragma unroll
  for (int d = 0; d < 6; ++d) acc[kk++] = w * v[d];
#pragma unroll
  for (int d = 0; d < 6; ++d) {
    float wv = w * v[d];
#pragma unroll
    for (int e = d; e < 6; ++e) acc[kk++] = wv * v[e];
  }
}

// ==== D1: pack (128 blocks x 256 pts). Redundant 13-max pass -> s, eps0;
// ==== packs points, writes per-block mom1 partials (no atomics, no init).
__global__ __launch_bounds__(256) void pack_kernel(
    const float* __restrict__ x, const float* __restrict__ y,
    float* __restrict__ sc, float* __restrict__ out,
    float* __restrict__ V6, float* __restrict__ Q,
    uint4* __restrict__ AREC, uint4* __restrict__ BRECA,
    float* __restrict__ MOMP1) {
  const int t = threadIdx.x, blk = blockIdx.x;
  const int wave = t >> 6, lane = t & 63;
  __shared__ float sh13[4][13];
  __shared__ float shfin[13];
  __shared__ float shm[4][28];

  // pass A: redundant global 13 maxes (inputs are L2/L3 resident)
  float e[13];
#pragma unroll
  for (int k = 0; k < 13; ++k) e[k] = -3.0e38f;
  for (int i = t; i < PTS; i += 256) {
    bool isx = i < ROWS;
    const float2* p2 =
        (const float2*)((isx ? x : y) + (size_t)(isx ? i : i - ROWS) * 6);
    float2 a = p2[0], b = p2[1], c = p2[2];
    float d[6] = {a.x, a.y, b.x, b.y, c.x, c.y};
    e[0] = fmaxf(e[0], d[0] * d[0] + d[1] * d[1] + d[2] * d[2]);
#pragma unroll
    for (int k = 0; k < 6; ++k) {
      e[1 + k] = fmaxf(e[1 + k], d[k]);
      e[7 + k] = fmaxf(e[7 + k], -d[k]);
    }
  }
#pragma unroll
  for (int off = 32; off > 0; off >>= 1) {
#pragma unroll
    for (int k = 0; k < 13; ++k) e[k] = fmaxf(e[k], __shfl_xor(e[k], off));
  }
  if (lane == 0) {
#pragma unroll
    for (int k = 0; k < 13; ++k) sh13[wave][k] = e[k];
  }
  __syncthreads();
  if (t < 13)
    shfin[t] = fmaxf(fmaxf(sh13[0][t], sh13[1][t]),
                     fmaxf(sh13[2][t], sh13[3][t]));
  __syncthreads();
  float eps0 = 0.0f;
#pragma unroll
  for (int k = 0; k < 6; ++k) {
    float dd = shfin[1 + k] + shfin[7 + k];   // max - min
    eps0 += dd * dd;
  }
  const float s = 1.0f / (sqrtf(shfin[0]) + 1e-6f);
  if (blk == 0 && t == 0) { sc[0] = eps0; out[0] = 0.0f; }

  // pass B: own 256 points
  const int idx = blk * 256 + t;
  bool isx = idx < ROWS;
  const float* p = (isx ? x : y) + (size_t)(isx ? idx : idx - ROWS) * 6;
  float v[6];
  v[0] = p[0] * s; v[1] = p[1] * s; v[2] = p[2] * s;
  v[3] = 0.1f * fminf(fmaxf(p[3], 0.0f), 1.0f);
  v[4] = 0.1f * fminf(fmaxf(p[4], 0.0f), 1.0f);
  v[5] = 0.1f * fminf(fmaxf(p[5], 0.0f), 1.0f);
  float q = v[0]*v[0] + v[1]*v[1] + v[2]*v[2] + v[3]*v[3] + v[4]*v[4] + v[5]*v[5];
  Q[idx] = q;
  float2* vp = (float2*)(V6 + (size_t)idx * 6);
  vp[0] = make_float2(v[0], v[1]);
  vp[1] = make_float2(v[2], v[3]);
  vp[2] = make_float2(v[4], v[5]);
  unsigned w01 = pkh2(v[0], v[1]), w23 = pkh2(v[2], v[3]),
           w45 = pkh2(v[4], v[5]);
  AREC[idx]  = (uint4){w01, w23, w45, pkh2(1.0f, 0.0f)};
  BRECA[idx] = (uint4){w01, w23, w45, 0u};

  float acc[28];
  mom_acc(fexp2(NEG_LOG2M - q * (LOG2E / eps0)), v, acc);
#pragma unroll
  for (int off = 32; off > 0; off >>= 1) {
#pragma unroll
    for (int k = 0; k < 28; ++k) acc[k] += __shfl_xor(acc[k], off);
  }
  if (lane == 0) {
#pragma unroll
    for (int k = 0; k < 28; ++k) shm[wave][k] = acc[k];
  }
  __syncthreads();
  if (t < 28)
    MOMP1[blk * 32 + t] = (shm[0][t] + shm[1][t]) + (shm[2][t] + shm[3][t]);
}

// ==== D2: rows1 (128 blocks): reduce opposite-group mom1, f1, mom2 partials
__global__ __launch_bounds__(256) void rows1_kernel(
    const float* __restrict__ sc, const float* __restrict__ V6,
    const float* __restrict__ Q, const float* __restrict__ MOMP1,
    float* __restrict__ MOMP2, float* __restrict__ FG1) {
  const int t = threadIdx.x, blk = blockIdx.x;
  const int wave = t >> 6, lane = t & 63;
  const int idx = blk * 256 + t;
  const int side = idx >> 14, batch = (idx >> 12) & 3;
  __shared__ float shfin[28];
  __shared__ float shm[4][28];

  const int ob0 = ((side ^ 1) * 4 + batch) * 16;   // 16 point-blocks / group
  if (t < 28) {
    float ssum = 0.0f;
#pragma unroll
    for (int b = 0; b < 16; ++b) ssum += MOMP1[(ob0 + b) * 32 + t];
    shfin[t] = ssum;
  }
  __syncthreads();
  const float eps0 = sc[0];
  const float2* vp = (const float2*)(V6 + (size_t)idx * 6);
  float2 a = vp[0], b2 = vp[1], c = vp[2];
  float v[6] = {a.x, a.y, b2.x, b2.y, c.x, c.y};
  float q = Q[idx];
  float S = taylor_S(shfin, v, eps0);
  float f1 = q - eps0 * LN2 * flog2(S);
  FG1[idx] = f1;
  float w2 = (1.0f / 4096.0f) / S;     // == 2^(NEG_LOG2M + (f1-q)*log2e/eps0)
  float acc[28];
  mom_acc(w2, v, acc);
#pragma unroll
  for (int off = 32; off > 0; off >>= 1) {
#pragma unroll
    for (int k = 0; k < 28; ++k) acc[k] += __shfl_xor(acc[k], off);
  }
  if (lane == 0) {
#pragma unroll
    for (int k = 0; k < 28; ++k) shm[wave][k] = acc[k];
  }
  __syncthreads();
  if (t < 28)
    MOMP2[blk * 32 + t] = (shm[0][t] + shm[1][t]) + (shm[2][t] + shm[3][t]);
}

// ==== D3: rows2 (128 blocks): reduce mom2, f2 -> FG2, hs2 -> BRECA.w =======
__global__ __launch_bounds__(256) void rows2_kernel(
    const float* __restrict__ sc, const float* __restrict__ V6,
    const float* __restrict__ Q, const float* __restrict__ MOMP2,
    const float* __restrict__ FG1, float* __restrict__ FG2,
    unsigned* __restrict__ BRECAu) {
  const int t = threadIdx.x, blk = blockIdx.x;
  const int idx = blk * 256 + t;
  const int side = idx >> 14, batch = (idx >> 12) & 3;
  __shared__ float shfin[28];
  const int ob0 = ((side ^ 1) * 4 + batch) * 16;
  if (t < 28) {
    float ssum = 0.0f;
#pragma unroll
    for (int b = 0; b < 16; ++b) ssum += MOMP2[(ob0 + b) * 32 + t];
    shfin[t] = ssum;
  }
  __syncthreads();
  const float eps0 = sc[0];
  const float2* vp = (const float2*)(V6 + (size_t)idx * 6);
  float2 a = vp[0], b2 = vp[1], c = vp[2];
  float v[6] = {a.x, a.y, b2.x, b2.y, c.x, c.y};
  float q = Q[idx];
  float S = taylor_S(shfin, v, eps0);
  float f_t = q - eps0 * LN2 * flog2(S);
  float f2v = 0.5f * (FG1[idx] + f_t);
  FG2[idx] = f2v;
  BRECAu[4 * idx + 3] = pkh2(0.5f * (f2v - q - EPS1LNM), 0.0f);
}

// ==== D4/D5: eps1 softmin via MFMA (512 blocks x 64 rows) ==================
// sm3 (BOUT!=0): fo = 0.5(FG2 + q - 2m) -> BRECB with hs3.
// sm4 (BOUT==0): fo = q - 2m -> wave-sum -> one atomicAdd(out) per block.
__global__ __launch_bounds__(256) void smax_kernel(
    const uint4* __restrict__ AREC, const uint4* __restrict__ BIN,
    uint4* __restrict__ BOUT, const float* __restrict__ Q,
    const float* __restrict__ FG2, float* __restrict__ out) {
  const int t = threadIdx.x;
  const int wave = t >> 6, lane = t & 63, l16 = lane & 15;
  const bool ld = lane < 16;
  const int grow0 = blockIdx.x * 64;
  const int side = grow0 >> 14, batch = (grow0 >> 12) & 3;
  const int colrec0 = (side ^ 1) * ROWS + batch * 4096 + wave * 1024;
  const uint4 z4 = (uint4){0u, 0u, 0u, 0u};
  v8h a[4];
#pragma unroll
  for (int i = 0; i < 4; ++i) {
    uint4 au = z4;
    if (ld) au = AREC[grow0 + i * 16 + l16];
    a[i] = bcv8(au);
  }
  const f32x4 cz = {0.0f, 0.0f, 0.0f, 0.0f};
  f32x4 m2[4];
#pragma unroll
  for (int i = 0; i < 4; ++i)
    m2[i] = (f32x4){-3.0e38f, -3.0e38f, -3.0e38f, -3.0e38f};

#pragma unroll 4
  for (int tt = 0; tt < 64; ++tt) {
    uint4 bu = z4;
    if (ld) bu = BIN[colrec0 + tt * 16 + l16];
    v8h b = bcv8(bu);
#pragma unroll
    for (int i = 0; i < 4; ++i) {
      f32x4 d = __builtin_amdgcn_mfma_f32_16x16x32_f16(a[i], b, cz, 0, 0, 0);
      m2[i] = __builtin_elementwise_max(m2[i], d);
    }
  }
#pragma unroll
  for (int off = 1; off <= 8; off <<= 1) {
#pragma unroll
    for (int i = 0; i < 4; ++i) {
#pragma unroll
      for (int r = 0; r < 4; ++r)
        m2[i][r] = fmaxf(m2[i][r], __shfl_xor(m2[i][r], off));
    }
  }
  __shared__ float lm[4][64];
  if (l16 == 0) {
    int qd = lane >> 4;
#pragma unroll
    for (int i = 0; i < 4; ++i) {
#pragma unroll
      for (int r = 0; r < 4; ++r) lm[wave][i * 16 + qd * 4 + r] = m2[i][r];
    }
  }
  __syncthreads();
  if (t < 64) {
    int g = grow0 + t;
    float m = fmaxf(fmaxf(lm[0][t], lm[1][t]), fmaxf(lm[2][t], lm[3][t]));
    float q = Q[g];
    if (BOUT) {
      float fo = 0.5f * (FG2[g] + (q - 2.0f * m));
      uint4 ar = AREC[g];
      BOUT[g] = (uint4){ar.x, ar.y, ar.z,
                        pkh2(0.5f * (fo - q - EPS1LNM), 0.0f)};
    } else {
      float fo = q - 2.0f * m;
#pragma unroll
      for (int off = 32; off > 0; off >>= 1) fo += __shfl_xor(fo, off);
      if (lane == 0) atomicAdd(out, fo * (10.0f / (float)ROWS));
    }
  }
}

extern "C" void kernel_launch(void* const* d_in, const int* in_sizes, int n_in,
                              void* d_out, int out_size, void* d_ws,
                              size_t ws_size, hipStream_t stream) {
  const float* x = (const float*)d_in[0];
  const float* y = (const float*)d_in[1];
  float* out = (float*)d_out;
  float* w = (float*)d_ws;
  float* sc    = w;                           // sc[0] = eps0
  float* MOMP1 = w + 1024;                    // 128*32
  float* MOMP2 = w + 6144;                    // 128*32
  float* base  = w + 16384;
  uint4* AREC  = (uint4*)base;                // 32768 * 16 B
  uint4* BRECA = (uint4*)(base + 131072);
  uint4* BRECB = (uint4*)(base + 262144);
  float* Q     = base + 393216;               // 32768
  float* FG1   = Q + PTS;                     // 32768
  float* FG2   = FG1 + PTS;                   // 32768
  float* V6    = FG2 + PTS;                   // 196608

  pack_kernel<<<128, 256, 0, stream>>>(x, y, sc, out, V6, Q, AREC, BRECA,
                                       MOMP1);
  rows1_kernel<<<128, 256, 0, stream>>>(sc, V6, Q, MOMP1, MOMP2, FG1);
  rows2_kernel<<<128, 256, 0, stream>>>(sc, V6, Q, MOMP2, FG1, FG2,
                                        (unsigned*)BRECA);
  smax_kernel<<<512, 256, 0, stream>>>(AREC, BRECA, BRECB, Q, FG2, nullptr);
  smax_kernel<<<512, 256, 0, stream>>>(AREC, BRECB, nullptr, Q, nullptr, out);
}